// Round 1
// baseline (302.613 us; speedup 1.0000x reference)
//
#include <hip/hip_runtime.h>
#include <hip/hip_bf16.h>

// Problem constants
#define NDIM 256   // outer n
#define QDIM 256   // q/k sequence
#define CDIM 128   // channels
#define HH 4       // heads
#define DD 32      // head dim
#define RROWS (NDIM * QDIM)  // 65536 flattened rows

// ---------- bf16 helpers (raw ushort storage, fp32 compute) ----------
__device__ __forceinline__ float bf2f(unsigned short u) {
    unsigned int x = ((unsigned int)u) << 16;
    return __uint_as_float(x);
}
__device__ __forceinline__ unsigned short f2bf(float f) {
    unsigned int x = __float_as_uint(f);
    unsigned int lsb = (x >> 16) & 1u;
    x += 0x7fffu + lsb;   // round-to-nearest-even
    return (unsigned short)(x >> 16);
}

// MFMA fragment types (gfx950: mfma_f32_16x16x32_bf16)
typedef __bf16 bf16x8v __attribute__((ext_vector_type(8)));
typedef float  f32x4v  __attribute__((ext_vector_type(4)));
union frag_u { uint4 u; bf16x8v v; };

__device__ __forceinline__ bf16x8v cvt8(float4 f0, float4 f1) {
    bf16x8v r;
    r[0] = (__bf16)f0.x; r[1] = (__bf16)f0.y; r[2] = (__bf16)f0.z; r[3] = (__bf16)f0.w;
    r[4] = (__bf16)f1.x; r[5] = (__bf16)f1.y; r[6] = (__bf16)f1.z; r[7] = (__bf16)f1.w;
    return r;
}

// =====================================================================
// Kernel 0: weight prep. 40 blocks (5 matrices x 8 k-chunks of 16).
// wt[p][n][k] = bf16(W_p[k][n])   (transposed so B-frags are contiguous)
// Was 5 blocks (serial-latency bound on 5 CUs); now 40.
// =====================================================================
__global__ __launch_bounds__(256, 1) void prep_weights(
    const float* __restrict__ Wq, const float* __restrict__ Wk,
    const float* __restrict__ Wv, const float* __restrict__ Wg,
    const float* __restrict__ Wo, unsigned short* __restrict__ wt)
{
    __shared__ unsigned short t[16][130];   // pad 130: conflict-free column reads
    const int p  = blockIdx.x >> 3;
    const int ch = blockIdx.x & 7;          // 16-row k-chunk
    const float* __restrict__ W = (p == 0) ? Wq : (p == 1) ? Wk :
                                  (p == 2) ? Wv : (p == 3) ? Wg : Wo;
    const int tid = threadIdx.x;
    for (int idx = tid; idx < 2048; idx += 256) {
        int k = idx >> 7, n = idx & 127;
        t[k][n] = f2bf(W[(ch * 16 + k) * 128 + n]);
    }
    __syncthreads();
    unsigned short* dst = wt + (size_t)p * 16384;
    for (int idx = tid; idx < 2048; idx += 256) {
        int n = idx >> 4, k = idx & 15;
        dst[n * 128 + ch * 16 + k] = t[k][n];   // Wt[n][k] = W[k][n]
    }
}

// =====================================================================
// Kernel 1: fused MFMA projections. grid (RROWS/64, 2), 256 thr.
//   pp=0: X=qx  -> q (scaled) and g (sigmoid)
//   pp=1: X=kvx -> k and v
// Latency-tolerance rework vs prev round:
//   - 16 rows/wave (was 32): acc 64 regs (was 128) -> 3 waves/SIMD
//   - all 8 A-loads issued up-front (fire-and-forget), convert after
//   - B loads in one fully-unrolled 64-load loop for deep scheduling
// =====================================================================
__global__ __launch_bounds__(256, 3) void proj_mfma(
    const float* __restrict__ qx, const float* __restrict__ kvx,
    const unsigned short* __restrict__ wt,
    unsigned short* __restrict__ q_ws, unsigned short* __restrict__ k_ws,
    unsigned short* __restrict__ v_ws, unsigned short* __restrict__ g_ws)
{
    const int tid = threadIdx.x;
    const int pp = blockIdx.y;
    const float* __restrict__ X = pp ? kvx : qx;
    // pp=0: A-path = Wq (idx 0), B-path = Wg (idx 3)
    // pp=1: A-path = Wk (idx 1), B-path = Wv (idx 2)
    const unsigned short* __restrict__ WtA = wt + (size_t)(pp ? 1 : 0) * 16384;
    const unsigned short* __restrict__ WtB = wt + (size_t)(pp ? 2 : 3) * 16384;

    const int wv   = tid >> 6;
    const int lane = tid & 63;
    const int col  = lane & 15;
    const int quad = lane >> 4;
    const int r0   = blockIdx.x * 64 + wv * 16;   // this wave's 16 rows

    // ---- issue ALL A loads up front (8 x float4, back-to-back) ----
    const float* __restrict__ arow = X + (size_t)(r0 + col) * 128 + quad * 8;
    float4 f[4][2];
#pragma unroll
    for (int kt = 0; kt < 4; ++kt) {
        f[kt][0] = *(const float4*)(arow + kt * 32);
        f[kt][1] = *(const float4*)(arow + kt * 32 + 4);
    }
    frag_u a[4];
#pragma unroll
    for (int kt = 0; kt < 4; ++kt) a[kt].v = cvt8(f[kt][0], f[kt][1]);

    f32x4v accA[8], accB[8];
#pragma unroll
    for (int nt = 0; nt < 8; ++nt) {
        accA[nt] = (f32x4v){0.f, 0.f, 0.f, 0.f};
        accB[nt] = (f32x4v){0.f, 0.f, 0.f, 0.f};
    }

#pragma unroll
    for (int kt = 0; kt < 4; ++kt) {
#pragma unroll
        for (int nt = 0; nt < 8; ++nt) {
            frag_u b0, b1;
            b0.u = *(const uint4*)(WtA + (size_t)(nt * 16 + col) * 128 + kt * 32 + quad * 8);
            b1.u = *(const uint4*)(WtB + (size_t)(nt * 16 + col) * 128 + kt * 32 + quad * 8);
            accA[nt] = __builtin_amdgcn_mfma_f32_16x16x32_bf16(a[kt].v, b0.v, accA[nt], 0, 0, 0);
            accB[nt] = __builtin_amdgcn_mfma_f32_16x16x32_bf16(a[kt].v, b1.v, accB[nt], 0, 0, 0);
        }
    }

    // epilogue: C row = r0 + quad*4 + r; col n = nt*16 + col
#pragma unroll
    for (int r = 0; r < 4; ++r) {
        int row = r0 + quad * 4 + r;
        int n = row >> 8;
        int si = row & 255;
#pragma unroll
        for (int nt = 0; nt < 8; ++nt) {
            int c = nt * 16 + col;
            int h = c >> 5, d = c & 31;
            if (pp == 0) {
                float qv = accA[nt][r] * 0.17677669529663687f;  // 1/sqrt(32)
                q_ws[((size_t)(n * HH + h) * QDIM + si) * DD + d] = f2bf(qv);
                float s = 1.0f / (1.0f + __expf(-accB[nt][r]));
                g_ws[(size_t)row * 128 + c] = f2bf(s);
            } else {
                k_ws[((size_t)(n * HH + h) * QDIM + si) * DD + d] = f2bf(accA[nt][r]);
                v_ws[((size_t)(n * HH + h) * QDIM + si) * DD + d] = f2bf(accB[nt][r]);
            }
        }
    }
}

// =====================================================================
// Kernel 2: MFMA attention (unchanged).
// =====================================================================
__global__ __launch_bounds__(256, 3) void attn_kernel(
    const unsigned short* __restrict__ q_ws, const unsigned short* __restrict__ k_ws,
    const unsigned short* __restrict__ v_ws, const unsigned short* __restrict__ g_ws,
    const float* __restrict__ tri, const float* __restrict__ mb,
    unsigned short* __restrict__ o_ws)
{
    __shared__ unsigned short vl[32 * 264];   // V^T [d][key], 16.9 KB
    __shared__ unsigned short Pl[64 * 264];   // P [q][key],   33.8 KB
    __shared__ float sinv[4][16];             // per-wave 1/rowsum

    const int tid = threadIdx.x;
    const int qc = blockIdx.x;   // 0..3 (64-query chunk)
    const int n  = blockIdx.y;
    const int h  = blockIdx.z;
    const size_t base = (size_t)(n * HH + h) * QDIM * DD;

    // ---- Stage V^T into LDS
    for (int t = 0; t < 4; ++t) {
        int idx = tid + t * 256;
        int key = idx >> 2;
        int u = idx & 3;
        union { uint4 q; unsigned short s[8]; } raw;
        raw.q = *(const uint4*)(v_ws + base + (size_t)key * DD + u * 8);
#pragma unroll
        for (int j = 0; j < 8; ++j)
            vl[(u * 8 + j) * 264 + key] = raw.s[j];
    }

    const int wv   = tid >> 6;
    const int lane = tid & 63;
    const int col  = lane & 15;
    const int quad = lane >> 4;
    const int qg   = qc * 64 + wv * 16 + col;

    frag_u bq;
    bq.u = *(const uint4*)(q_ws + base + (size_t)qg * DD + quad * 8);

    f32x4v acc[16];
#pragma unroll
    for (int mt = 0; mt < 16; ++mt) {
        int k0 = mt * 16 + quad * 4;
        float4 t4 = *(const float4*)&tri[((size_t)(h * 256 + qg)) * 256 + k0];
        float4 m4 = *(const float4*)&mb[n * 256 + k0];
        f32x4v c;
        c[0] = t4.x + m4.x; c[1] = t4.y + m4.y;
        c[2] = t4.z + m4.z; c[3] = t4.w + m4.w;
        frag_u ak;
        ak.u = *(const uint4*)(k_ws + base + (size_t)(mt * 16 + col) * DD + quad * 8);
        acc[mt] = __builtin_amdgcn_mfma_f32_16x16x32_bf16(ak.v, bq.v, c, 0, 0, 0);
    }

    float mx = -1e30f;
#pragma unroll
    for (int mt = 0; mt < 16; ++mt)
#pragma unroll
        for (int r = 0; r < 4; ++r) mx = fmaxf(mx, acc[mt][r]);
    mx = fmaxf(mx, __shfl_xor(mx, 16));
    mx = fmaxf(mx, __shfl_xor(mx, 32));

    float sum = 0.f;
#pragma unroll
    for (int mt = 0; mt < 16; ++mt)
#pragma unroll
        for (int r = 0; r < 4; ++r) {
            float e = __expf(acc[mt][r] - mx);
            acc[mt][r] = e;
            sum += e;
        }
    sum += __shfl_xor(sum, 16);
    sum += __shfl_xor(sum, 32);
    if (quad == 0) sinv[wv][col] = 1.0f / sum;

#pragma unroll
    for (int mt = 0; mt < 16; ++mt) {
        ushort4 pk;
        pk.x = f2bf(acc[mt][0]); pk.y = f2bf(acc[mt][1]);
        pk.z = f2bf(acc[mt][2]); pk.w = f2bf(acc[mt][3]);
        *(ushort4*)&Pl[(wv * 16 + col) * 264 + mt * 16 + quad * 4] = pk;
    }

    __syncthreads();

    f32x4v o0 = {0.f, 0.f, 0.f, 0.f};
    f32x4v o1 = {0.f, 0.f, 0.f, 0.f};
#pragma unroll
    for (int kc = 0; kc < 8; ++kc) {
        frag_u ap, b0, b1;
        ap.u = *(const uint4*)&Pl[(wv * 16 + col) * 264 + kc * 32 + quad * 8];
        b0.u = *(const uint4*)&vl[(col) * 264 + kc * 32 + quad * 8];
        b1.u = *(const uint4*)&vl[(16 + col) * 264 + kc * 32 + quad * 8];
        o0 = __builtin_amdgcn_mfma_f32_16x16x32_bf16(ap.v, b0.v, o0, 0, 0, 0);
        o1 = __builtin_amdgcn_mfma_f32_16x16x32_bf16(ap.v, b1.v, o1, 0, 0, 0);
    }

#pragma unroll
    for (int r = 0; r < 4; ++r) {
        int qi = quad * 4 + r;
        int qglob = qc * 64 + wv * 16 + qi;
        float iv = sinv[wv][qi];
        size_t ob = ((size_t)(n * 256 + qglob)) * 128 + h * 32;
        float g0 = bf2f(g_ws[ob + col]);
        o_ws[ob + col] = f2bf(o0[r] * iv * g0);
        float g1 = bf2f(g_ws[ob + 16 + col]);
        o_ws[ob + 16 + col] = f2bf(o1[r] * iv * g1);
    }
}

// =====================================================================
// Kernel 3: MFMA out-projection. grid RROWS/64, 256 thr, no LDS.
// Same latency rework: 16 rows/wave, all A-loads up front.
// out[65536x128] fp32 = o_ws(bf16) @ Wo  (B-frags from wt[4])
// =====================================================================
__global__ __launch_bounds__(256, 4) void outproj_mfma(
    const unsigned short* __restrict__ o_ws, const unsigned short* __restrict__ wt,
    float* __restrict__ out)
{
    const int tid = threadIdx.x;
    const unsigned short* __restrict__ Wt = wt + 4 * 16384;

    const int wv   = tid >> 6;
    const int lane = tid & 63;
    const int col  = lane & 15;
    const int quad = lane >> 4;
    const int r0   = blockIdx.x * 64 + wv * 16;

    // all 4 A-loads up front (bf16, no conversion needed)
    frag_u a[4];
    const unsigned short* __restrict__ arow = o_ws + (size_t)(r0 + col) * 128 + quad * 8;
#pragma unroll
    for (int kt = 0; kt < 4; ++kt)
        a[kt].u = *(const uint4*)(arow + kt * 32);

    f32x4v acc[8];
#pragma unroll
    for (int nt = 0; nt < 8; ++nt)
        acc[nt] = (f32x4v){0.f, 0.f, 0.f, 0.f};

#pragma unroll
    for (int kt = 0; kt < 4; ++kt) {
#pragma unroll
        for (int nt = 0; nt < 8; ++nt) {
            frag_u b;
            b.u = *(const uint4*)(Wt + (size_t)(nt * 16 + col) * 128 + kt * 32 + quad * 8);
            acc[nt] = __builtin_amdgcn_mfma_f32_16x16x32_bf16(a[kt].v, b.v, acc[nt], 0, 0, 0);
        }
    }

#pragma unroll
    for (int r = 0; r < 4; ++r) {
        size_t row = r0 + quad * 4 + r;
#pragma unroll
        for (int nt = 0; nt < 8; ++nt)
            out[row * 128 + nt * 16 + col] = acc[nt][r];
    }
}

// =====================================================================
extern "C" void kernel_launch(void* const* d_in, const int* in_sizes, int n_in,
                              void* d_out, int out_size, void* d_ws, size_t ws_size,
                              hipStream_t stream) {
    const float* qx  = (const float*)d_in[0];
    const float* kvx = (const float*)d_in[1];
    const float* tri = (const float*)d_in[2];
    const float* mb  = (const float*)d_in[3];
    // d_in[4] = mask (unused: mask_bias carries it in the reference path)
    const float* Wq  = (const float*)d_in[5];
    const float* Wk  = (const float*)d_in[6];
    const float* Wv  = (const float*)d_in[7];
    const float* Wg  = (const float*)d_in[8];
    const float* Wo  = (const float*)d_in[9];
    float* out = (float*)d_out;

    unsigned short* ws = (unsigned short*)d_ws;
    const size_t RC = (size_t)RROWS * 128;
    unsigned short* q_ws = ws;            // [n][h][q][32]
    unsigned short* k_ws = ws + RC;       // [n][h][k][32]
    unsigned short* v_ws = ws + 2 * RC;   // [n][h][k][32]
    unsigned short* g_ws = ws + 3 * RC;   // [n][q][128]
    unsigned short* o_ws = ws + 4 * RC;   // [n][q][128]
    unsigned short* wt   = ws + 5 * RC;   // 5 x [128][128] bf16 transposed weights

    prep_weights<<<dim3(40), 256, 0, stream>>>(Wq, Wk, Wv, Wg, Wo, wt);
    proj_mfma<<<dim3(RROWS / 64, 2), 256, 0, stream>>>(
        qx, kvx, wt, q_ws, k_ws, v_ws, g_ws);
    attn_kernel<<<dim3(4, NDIM, HH), 256, 0, stream>>>(
        q_ws, k_ws, v_ws, g_ws, tri, mb, o_ws);
    outproj_mfma<<<dim3(RROWS / 64), 256, 0, stream>>>(o_ws, wt, out);
}

// Round 2
// 247.888 us; speedup vs baseline: 1.2208x; 1.2208x over previous
//
#include <hip/hip_runtime.h>
#include <hip/hip_bf16.h>

// Problem constants
#define NDIM 256   // outer n
#define QDIM 256   // q/k sequence
#define CDIM 128   // channels
#define HH 4       // heads
#define DD 32      // head dim
#define RROWS (NDIM * QDIM)  // 65536 flattened rows

// ---------- bf16 helpers (raw ushort storage, fp32 compute) ----------
__device__ __forceinline__ float bf2f(unsigned short u) {
    unsigned int x = ((unsigned int)u) << 16;
    return __uint_as_float(x);
}
__device__ __forceinline__ unsigned short f2bf(float f) {
    unsigned int x = __float_as_uint(f);
    unsigned int lsb = (x >> 16) & 1u;
    x += 0x7fffu + lsb;   // round-to-nearest-even
    return (unsigned short)(x >> 16);
}

// MFMA fragment types (gfx950: mfma_f32_16x16x32_bf16)
typedef __bf16 bf16x8v __attribute__((ext_vector_type(8)));
typedef float  f32x4v  __attribute__((ext_vector_type(4)));
union frag_u { uint4 u; bf16x8v v; };

__device__ __forceinline__ bf16x8v cvt8(float4 f0, float4 f1) {
    bf16x8v r;
    r[0] = (__bf16)f0.x; r[1] = (__bf16)f0.y; r[2] = (__bf16)f0.z; r[3] = (__bf16)f0.w;
    r[4] = (__bf16)f1.x; r[5] = (__bf16)f1.y; r[6] = (__bf16)f1.z; r[7] = (__bf16)f1.w;
    return r;
}

// =====================================================================
// Kernel 0: weight prep. 40 blocks (5 matrices x 8 k-chunks of 16).
// wt[p][n][k] = bf16(W_p[k][n])   (transposed so B-frags are contiguous)
// =====================================================================
__global__ __launch_bounds__(256, 1) void prep_weights(
    const float* __restrict__ Wq, const float* __restrict__ Wk,
    const float* __restrict__ Wv, const float* __restrict__ Wg,
    const float* __restrict__ Wo, unsigned short* __restrict__ wt)
{
    __shared__ unsigned short t[16][130];   // pad 130: conflict-free column reads
    const int p  = blockIdx.x >> 3;
    const int ch = blockIdx.x & 7;          // 16-row k-chunk
    const float* __restrict__ W = (p == 0) ? Wq : (p == 1) ? Wk :
                                  (p == 2) ? Wv : (p == 3) ? Wg : Wo;
    const int tid = threadIdx.x;
    for (int idx = tid; idx < 2048; idx += 256) {
        int k = idx >> 7, n = idx & 127;
        t[k][n] = f2bf(W[(ch * 16 + k) * 128 + n]);
    }
    __syncthreads();
    unsigned short* dst = wt + (size_t)p * 16384;
    for (int idx = tid; idx < 2048; idx += 256) {
        int n = idx >> 4, k = idx & 15;
        dst[n * 128 + ch * 16 + k] = t[k][n];   // Wt[n][k] = W[k][n]
    }
}

// =====================================================================
// Kernel 1: fused MFMA projections. grid (RROWS/128, 2), 512 thr.
//   pp=0: X=qx  -> q (scaled) and g (sigmoid)
//   pp=1: X=kvx -> k and v
// Round-2 restructure: weights LDS-resident (64 KB, XOR-swizzled so
// ds_read_b128 frag reads are bank-uniform). A-loads issued before the
// staging barrier so HBM latency hides under the stage. This removes
// the 64-dependent-global-load chain that made each wave ~20 us.
// =====================================================================
__global__ __launch_bounds__(512, 4) void proj_mfma(
    const float* __restrict__ qx, const float* __restrict__ kvx,
    const unsigned short* __restrict__ wt,
    unsigned short* __restrict__ q_ws, unsigned short* __restrict__ k_ws,
    unsigned short* __restrict__ v_ws, unsigned short* __restrict__ g_ws)
{
    __shared__ unsigned short wl[2 * 16384];   // 64 KB: WtA | WtB, swizzled
    const int tid = threadIdx.x;               // 0..511
    const int pp = blockIdx.y;
    const float* __restrict__ X = pp ? kvx : qx;
    // pp=0: A-path = Wq (idx 0), B-path = Wg (idx 3)
    // pp=1: A-path = Wk (idx 1), B-path = Wv (idx 2)
    const unsigned short* __restrict__ WtA = wt + (size_t)(pp ? 1 : 0) * 16384;
    const unsigned short* __restrict__ WtB = wt + (size_t)(pp ? 2 : 3) * 16384;

    const int wv   = tid >> 6;     // 0..7
    const int lane = tid & 63;
    const int col  = lane & 15;
    const int quad = lane >> 4;
    const int r0   = blockIdx.x * 128 + wv * 16;   // this wave's 16 rows

    // ---- issue ALL A loads first: in flight during staging+barrier ----
    const float* __restrict__ arow = X + (size_t)(r0 + col) * 128 + quad * 8;
    float4 f[4][2];
#pragma unroll
    for (int kt = 0; kt < 4; ++kt) {
        f[kt][0] = *(const float4*)(arow + kt * 32);
        f[kt][1] = *(const float4*)(arow + kt * 32 + 4);
    }

    // ---- stage both weight matrices into LDS (swizzled slots) ----
    // layout: wl[mat*16384 + r*128 + ((s ^ (r&7)) * 8)], s = 16B slot 0..15
#pragma unroll
    for (int i = 0; i < 8; ++i) {
        int v = i * 512 + tid;           // 0..4095 uint4 tiles
        int mat = v >> 11;
        int r = (v >> 4) & 127;
        int s = v & 15;
        const unsigned short* src = (mat ? WtB : WtA) + r * 128 + s * 8;
        uint4 d = *(const uint4*)src;
        *(uint4*)&wl[mat * 16384 + r * 128 + ((s ^ (r & 7)) << 3)] = d;
    }
    __syncthreads();

    frag_u a[4];
#pragma unroll
    for (int kt = 0; kt < 4; ++kt) a[kt].v = cvt8(f[kt][0], f[kt][1]);

    f32x4v accA[8], accB[8];
#pragma unroll
    for (int nt = 0; nt < 8; ++nt) {
        accA[nt] = (f32x4v){0.f, 0.f, 0.f, 0.f};
        accB[nt] = (f32x4v){0.f, 0.f, 0.f, 0.f};
    }

    const int x7 = col & 7;
#pragma unroll
    for (int kt = 0; kt < 4; ++kt) {
#pragma unroll
        for (int nt = 0; nt < 8; ++nt) {
            // B-frag row = nt*16+col; row&7 == col&7, so the xor term is
            // independent of nt: slot_phys = (kt*4+quad) ^ (col&7)
            int off = nt * 2048 + col * 128 + ((((kt << 2) | quad) ^ x7) << 3);
            frag_u b0, b1;
            b0.u = *(const uint4*)&wl[off];
            b1.u = *(const uint4*)&wl[16384 + off];
            accA[nt] = __builtin_amdgcn_mfma_f32_16x16x32_bf16(a[kt].v, b0.v, accA[nt], 0, 0, 0);
            accB[nt] = __builtin_amdgcn_mfma_f32_16x16x32_bf16(a[kt].v, b1.v, accB[nt], 0, 0, 0);
        }
    }

    // epilogue: C row = r0 + quad*4 + r; col n = nt*16 + col
#pragma unroll
    for (int r = 0; r < 4; ++r) {
        int row = r0 + quad * 4 + r;
        int n = row >> 8;
        int si = row & 255;
#pragma unroll
        for (int nt = 0; nt < 8; ++nt) {
            int c = nt * 16 + col;
            int h = c >> 5, d = c & 31;
            if (pp == 0) {
                float qv = accA[nt][r] * 0.17677669529663687f;  // 1/sqrt(32)
                q_ws[((size_t)(n * HH + h) * QDIM + si) * DD + d] = f2bf(qv);
                float s = 1.0f / (1.0f + __expf(-accB[nt][r]));
                g_ws[(size_t)row * 128 + c] = f2bf(s);
            } else {
                k_ws[((size_t)(n * HH + h) * QDIM + si) * DD + d] = f2bf(accA[nt][r]);
                v_ws[((size_t)(n * HH + h) * QDIM + si) * DD + d] = f2bf(accB[nt][r]);
            }
        }
    }
}

// =====================================================================
// Kernel 2: MFMA attention (unchanged).
// =====================================================================
__global__ __launch_bounds__(256, 3) void attn_kernel(
    const unsigned short* __restrict__ q_ws, const unsigned short* __restrict__ k_ws,
    const unsigned short* __restrict__ v_ws, const unsigned short* __restrict__ g_ws,
    const float* __restrict__ tri, const float* __restrict__ mb,
    unsigned short* __restrict__ o_ws)
{
    __shared__ unsigned short vl[32 * 264];   // V^T [d][key], 16.9 KB
    __shared__ unsigned short Pl[64 * 264];   // P [q][key],   33.8 KB
    __shared__ float sinv[4][16];             // per-wave 1/rowsum

    const int tid = threadIdx.x;
    const int qc = blockIdx.x;   // 0..3 (64-query chunk)
    const int n  = blockIdx.y;
    const int h  = blockIdx.z;
    const size_t base = (size_t)(n * HH + h) * QDIM * DD;

    // ---- Stage V^T into LDS
    for (int t = 0; t < 4; ++t) {
        int idx = tid + t * 256;
        int key = idx >> 2;
        int u = idx & 3;
        union { uint4 q; unsigned short s[8]; } raw;
        raw.q = *(const uint4*)(v_ws + base + (size_t)key * DD + u * 8);
#pragma unroll
        for (int j = 0; j < 8; ++j)
            vl[(u * 8 + j) * 264 + key] = raw.s[j];
    }

    const int wv   = tid >> 6;
    const int lane = tid & 63;
    const int col  = lane & 15;
    const int quad = lane >> 4;
    const int qg   = qc * 64 + wv * 16 + col;

    frag_u bq;
    bq.u = *(const uint4*)(q_ws + base + (size_t)qg * DD + quad * 8);

    f32x4v acc[16];
#pragma unroll
    for (int mt = 0; mt < 16; ++mt) {
        int k0 = mt * 16 + quad * 4;
        float4 t4 = *(const float4*)&tri[((size_t)(h * 256 + qg)) * 256 + k0];
        float4 m4 = *(const float4*)&mb[n * 256 + k0];
        f32x4v c;
        c[0] = t4.x + m4.x; c[1] = t4.y + m4.y;
        c[2] = t4.z + m4.z; c[3] = t4.w + m4.w;
        frag_u ak;
        ak.u = *(const uint4*)(k_ws + base + (size_t)(mt * 16 + col) * DD + quad * 8);
        acc[mt] = __builtin_amdgcn_mfma_f32_16x16x32_bf16(ak.v, bq.v, c, 0, 0, 0);
    }

    float mx = -1e30f;
#pragma unroll
    for (int mt = 0; mt < 16; ++mt)
#pragma unroll
        for (int r = 0; r < 4; ++r) mx = fmaxf(mx, acc[mt][r]);
    mx = fmaxf(mx, __shfl_xor(mx, 16));
    mx = fmaxf(mx, __shfl_xor(mx, 32));

    float sum = 0.f;
#pragma unroll
    for (int mt = 0; mt < 16; ++mt)
#pragma unroll
        for (int r = 0; r < 4; ++r) {
            float e = __expf(acc[mt][r] - mx);
            acc[mt][r] = e;
            sum += e;
        }
    sum += __shfl_xor(sum, 16);
    sum += __shfl_xor(sum, 32);
    if (quad == 0) sinv[wv][col] = 1.0f / sum;

#pragma unroll
    for (int mt = 0; mt < 16; ++mt) {
        ushort4 pk;
        pk.x = f2bf(acc[mt][0]); pk.y = f2bf(acc[mt][1]);
        pk.z = f2bf(acc[mt][2]); pk.w = f2bf(acc[mt][3]);
        *(ushort4*)&Pl[(wv * 16 + col) * 264 + mt * 16 + quad * 4] = pk;
    }

    __syncthreads();

    f32x4v o0 = {0.f, 0.f, 0.f, 0.f};
    f32x4v o1 = {0.f, 0.f, 0.f, 0.f};
#pragma unroll
    for (int kc = 0; kc < 8; ++kc) {
        frag_u ap, b0, b1;
        ap.u = *(const uint4*)&Pl[(wv * 16 + col) * 264 + kc * 32 + quad * 8];
        b0.u = *(const uint4*)&vl[(col) * 264 + kc * 32 + quad * 8];
        b1.u = *(const uint4*)&vl[(16 + col) * 264 + kc * 32 + quad * 8];
        o0 = __builtin_amdgcn_mfma_f32_16x16x32_bf16(ap.v, b0.v, o0, 0, 0, 0);
        o1 = __builtin_amdgcn_mfma_f32_16x16x32_bf16(ap.v, b1.v, o1, 0, 0, 0);
    }

#pragma unroll
    for (int r = 0; r < 4; ++r) {
        int qi = quad * 4 + r;
        int qglob = qc * 64 + wv * 16 + qi;
        float iv = sinv[wv][qi];
        size_t ob = ((size_t)(n * 256 + qglob)) * 128 + h * 32;
        float g0 = bf2f(g_ws[ob + col]);
        o_ws[ob + col] = f2bf(o0[r] * iv * g0);
        float g1 = bf2f(g_ws[ob + 16 + col]);
        o_ws[ob + 16 + col] = f2bf(o1[r] * iv * g1);
    }
}

// =====================================================================
// Kernel 3: MFMA out-projection. grid RROWS/128, 512 thr.
// Same LDS-resident-weight restructure as proj_mfma (32 KB, swizzled).
// out[65536x128] fp32 = o_ws(bf16) @ Wo  (B-frags from wt[4])
// =====================================================================
__global__ __launch_bounds__(512, 4) void outproj_mfma(
    const unsigned short* __restrict__ o_ws, const unsigned short* __restrict__ wt,
    float* __restrict__ out)
{
    __shared__ unsigned short wl[16384];   // 32 KB swizzled Wo^T
    const int tid = threadIdx.x;           // 0..511
    const unsigned short* __restrict__ Wt = wt + 4 * 16384;

    const int wv   = tid >> 6;
    const int lane = tid & 63;
    const int col  = lane & 15;
    const int quad = lane >> 4;
    const int r0   = blockIdx.x * 128 + wv * 16;

    // A loads first (in flight during staging+barrier)
    frag_u a[4];
    const unsigned short* __restrict__ arow = o_ws + (size_t)(r0 + col) * 128 + quad * 8;
#pragma unroll
    for (int kt = 0; kt < 4; ++kt)
        a[kt].u = *(const uint4*)(arow + kt * 32);

    // stage Wo^T into LDS (swizzled)
#pragma unroll
    for (int i = 0; i < 4; ++i) {
        int v = i * 512 + tid;    // 0..2047
        int r = v >> 4;
        int s = v & 15;
        uint4 d = *(const uint4*)(Wt + r * 128 + s * 8);
        *(uint4*)&wl[r * 128 + ((s ^ (r & 7)) << 3)] = d;
    }
    __syncthreads();

    f32x4v acc[8];
#pragma unroll
    for (int nt = 0; nt < 8; ++nt)
        acc[nt] = (f32x4v){0.f, 0.f, 0.f, 0.f};

    const int x7 = col & 7;
#pragma unroll
    for (int kt = 0; kt < 4; ++kt) {
#pragma unroll
        for (int nt = 0; nt < 8; ++nt) {
            int off = nt * 2048 + col * 128 + ((((kt << 2) | quad) ^ x7) << 3);
            frag_u b;
            b.u = *(const uint4*)&wl[off];
            acc[nt] = __builtin_amdgcn_mfma_f32_16x16x32_bf16(a[kt].v, b.v, acc[nt], 0, 0, 0);
        }
    }

#pragma unroll
    for (int r = 0; r < 4; ++r) {
        size_t row = r0 + quad * 4 + r;
#pragma unroll
        for (int nt = 0; nt < 8; ++nt)
            out[row * 128 + nt * 16 + col] = acc[nt][r];
    }
}

// =====================================================================
extern "C" void kernel_launch(void* const* d_in, const int* in_sizes, int n_in,
                              void* d_out, int out_size, void* d_ws, size_t ws_size,
                              hipStream_t stream) {
    const float* qx  = (const float*)d_in[0];
    const float* kvx = (const float*)d_in[1];
    const float* tri = (const float*)d_in[2];
    const float* mb  = (const float*)d_in[3];
    // d_in[4] = mask (unused: mask_bias carries it in the reference path)
    const float* Wq  = (const float*)d_in[5];
    const float* Wk  = (const float*)d_in[6];
    const float* Wv  = (const float*)d_in[7];
    const float* Wg  = (const float*)d_in[8];
    const float* Wo  = (const float*)d_in[9];
    float* out = (float*)d_out;

    unsigned short* ws = (unsigned short*)d_ws;
    const size_t RC = (size_t)RROWS * 128;
    unsigned short* q_ws = ws;            // [n][h][q][32]
    unsigned short* k_ws = ws + RC;       // [n][h][k][32]
    unsigned short* v_ws = ws + 2 * RC;   // [n][h][k][32]
    unsigned short* g_ws = ws + 3 * RC;   // [n][q][128]
    unsigned short* o_ws = ws + 4 * RC;   // [n][q][128]
    unsigned short* wt   = ws + 5 * RC;   // 5 x [128][128] bf16 transposed weights

    prep_weights<<<dim3(40), 256, 0, stream>>>(Wq, Wk, Wv, Wg, Wo, wt);
    proj_mfma<<<dim3(RROWS / 128, 2), 512, 0, stream>>>(
        qx, kvx, wt, q_ws, k_ws, v_ws, g_ws);
    attn_kernel<<<dim3(4, NDIM, HH), 256, 0, stream>>>(
        q_ws, k_ws, v_ws, g_ws, tri, mb, o_ws);
    outproj_mfma<<<dim3(RROWS / 128), 512, 0, stream>>>(o_ws, wt, out);
}